// Round 1
// baseline (1070.839 us; speedup 1.0000x reference)
//
#include <hip/hip_runtime.h>
#include <hip/hip_bf16.h>
#include <math.h>

#define FEAT 512
#define SEGS_PER_BLOCK 4   // 4 waves of 64 per block, one segment per wave

// ---------------------------------------------------------------------------
// Kernel 1: init workspace (seg_first/seg_last = 0, v = 0). ws is poisoned
// 0xAA before every timed launch, so we must zero it ourselves.
// ---------------------------------------------------------------------------
__global__ void init_ws_kernel(int* __restrict__ seg_first,
                               int* __restrict__ seg_last,
                               float* __restrict__ v, int nseg) {
    int i = blockIdx.x * blockDim.x + threadIdx.x;
    if (i < nseg) { seg_first[i] = 0; seg_last[i] = 0; }
    if (i < FEAT) v[i] = 0.0f;
}

// ---------------------------------------------------------------------------
// Kernel 2: v[d] = sum_e W[e][d] * q[e]   (the algebraic collapse of the
// projection GEMM: scores = F·(W^T q) + const, const cancels in softmax).
// 64 blocks x 256 threads; block b handles 8 rows e, atomicAdd partials.
// ---------------------------------------------------------------------------
__global__ void vproj_kernel(const float* __restrict__ W,
                             const float* __restrict__ q,
                             float* __restrict__ v) {
    int d0 = threadIdx.x;        // 0..255
    int d1 = threadIdx.x + 256;  // 256..511
    float s0 = 0.0f, s1 = 0.0f;
    int e0 = blockIdx.x * 8;
#pragma unroll
    for (int k = 0; k < 8; ++k) {
        int e = e0 + k;
        float qe = q[e];
        s0 += W[e * FEAT + d0] * qe;
        s1 += W[e * FEAT + d1] * qe;
    }
    atomicAdd(&v[d0], s0);
    atomicAdd(&v[d1], s1);
}

// ---------------------------------------------------------------------------
// Kernel 3: segment boundaries. residue_index is sorted, so each segment is a
// contiguous run; the run edges are written by exactly one thread (no atomics).
// Empty segments keep first=last=0 from init -> zero-length range.
// ---------------------------------------------------------------------------
__global__ void bounds_kernel(const int* __restrict__ idx,
                              int* __restrict__ seg_first,
                              int* __restrict__ seg_last, int n) {
    int i = blockIdx.x * blockDim.x + threadIdx.x;
    if (i >= n) return;
    int r = idx[i];
    if (i == 0 || idx[i - 1] != r) seg_first[r] = i;
    if (i == n - 1 || idx[i + 1] != r) seg_last[r] = i + 1;
}

// ---------------------------------------------------------------------------
// Kernel 4: main. One wave (64 lanes) per segment; flash-style online softmax
// so features are read exactly ONCE from global. Lane l owns 8 feature
// columns (float4 at l and l+64 of the 128-float4 row). Per atom:
//   - coalesced 2 KB row load (2x dwordx4 per lane)
//   - dot with v (v fragment lives in 8 VGPRs, loaded once)
//   - 6-step butterfly shuffle reduce -> score broadcast to all lanes
//   - online-softmax update of running (m, denom) + rescale-accumulate of
//     the 8-float output fragment in registers.
// No LDS, no __syncthreads, handles any segment length.
// ---------------------------------------------------------------------------
__global__ __launch_bounds__(256) void
segment_softmax_reduce_kernel(const float* __restrict__ feat,
                              const float* __restrict__ v,
                              const int* __restrict__ seg_first,
                              const int* __restrict__ seg_last,
                              float* __restrict__ out, int nseg) {
    int wave = threadIdx.x >> 6;
    int lane = threadIdx.x & 63;
    int s = blockIdx.x * SEGS_PER_BLOCK + wave;
    if (s >= nseg) return;

    int first = seg_first[s];
    int last  = seg_last[s];

    const float4* v4 = (const float4*)v;
    float4 va = v4[lane];
    float4 vb = v4[lane + 64];

    float m = -INFINITY;
    float denom = 0.0f;
    float4 acc_a = make_float4(0.f, 0.f, 0.f, 0.f);
    float4 acc_b = make_float4(0.f, 0.f, 0.f, 0.f);

    for (int a = first; a < last; ++a) {
        const float4* f4 = (const float4*)(feat + (size_t)a * FEAT);
        float4 fa = f4[lane];
        float4 fb = f4[lane + 64];

        float p = fa.x * va.x + fa.y * va.y + fa.z * va.z + fa.w * va.w
                + fb.x * vb.x + fb.y * vb.y + fb.z * vb.z + fb.w * vb.w;
        // butterfly reduce: all 64 lanes end with the full dot product
#pragma unroll
        for (int off = 32; off > 0; off >>= 1)
            p += __shfl_xor(p, off, 64);

        float m_new = fmaxf(m, p);
        float alpha = __expf(m - m_new);   // first iter: exp(-inf)=0, state is 0 anyway
        float e     = __expf(p - m_new);
        denom = denom * alpha + e;
        acc_a.x = acc_a.x * alpha + e * fa.x;
        acc_a.y = acc_a.y * alpha + e * fa.y;
        acc_a.z = acc_a.z * alpha + e * fa.z;
        acc_a.w = acc_a.w * alpha + e * fa.w;
        acc_b.x = acc_b.x * alpha + e * fb.x;
        acc_b.y = acc_b.y * alpha + e * fb.y;
        acc_b.z = acc_b.z * alpha + e * fb.z;
        acc_b.w = acc_b.w * alpha + e * fb.w;
        m = m_new;
    }

    float inv = (last > first) ? 1.0f / denom : 0.0f;  // empty segment -> zeros
    float4 oa = make_float4(acc_a.x * inv, acc_a.y * inv, acc_a.z * inv, acc_a.w * inv);
    float4 ob = make_float4(acc_b.x * inv, acc_b.y * inv, acc_b.z * inv, acc_b.w * inv);
    float4* o4 = (float4*)(out + (size_t)s * FEAT);
    o4[lane]      = oa;
    o4[lane + 64] = ob;
}

// ---------------------------------------------------------------------------
extern "C" void kernel_launch(void* const* d_in, const int* in_sizes, int n_in,
                              void* d_out, int out_size, void* d_ws, size_t ws_size,
                              hipStream_t stream) {
    const float* features = (const float*)d_in[0];   // [N, 512] fp32
    const int*   ridx     = (const int*)d_in[1];     // [N] int (sorted)
    const float* proj_w   = (const float*)d_in[2];   // [512, 512] fp32
    // d_in[3] = proj_b : cancels inside the per-segment softmax -> unused
    const float* query    = (const float*)d_in[4];   // [512] fp32
    float* out = (float*)d_out;                      // [NSEG, 512] fp32

    const int n_atoms = in_sizes[1];
    const int nseg    = out_size / FEAT;

    // workspace layout: v[512] floats | seg_first[nseg] | seg_last[nseg]
    float* v        = (float*)d_ws;
    int*   seg_first = (int*)(v + FEAT);
    int*   seg_last  = seg_first + nseg;

    {
        int threads = 256;
        int blocks = (nseg + threads - 1) / threads;
        init_ws_kernel<<<blocks, threads, 0, stream>>>(seg_first, seg_last, v, nseg);
    }
    vproj_kernel<<<FEAT / 8, 256, 0, stream>>>(proj_w, query, v);
    {
        int threads = 256;
        int blocks = (n_atoms + threads - 1) / threads;
        bounds_kernel<<<blocks, threads, 0, stream>>>(ridx, seg_first, seg_last, n_atoms);
    }
    {
        int blocks = (nseg + SEGS_PER_BLOCK - 1) / SEGS_PER_BLOCK;
        segment_softmax_reduce_kernel<<<blocks, 256, 0, stream>>>(
            features, v, seg_first, seg_last, out, nseg);
    }
}